// Round 12
// baseline (1553.860 us; speedup 1.0000x reference)
//
#include <hip/hip_runtime.h>
#include <math.h>

#define H      1024
#define B      128
#define T      256
#define GROUPS 8        // 8 groups x 32 blocks = 256 blocks (1/CU target)
#define BPG    32       // blocks per group; block owns 32 dims = 128 gate rows
#define NTHR   512
#define MPG    16       // batches per group
#define DPB    32       // dims per block
#define GRP_SHORTS (MPG * H)               // 16384 shorts = 32KB per group per slot
#define GRP_STRIDE (GROUPS * GRP_SHORTS)   // shorts per h-ring slot (all groups)
#define HSLOTS 4
#define POISON 0x7F807F80u                 // bf16 +inf pair: unreachable by h=og*tanh(c)
#define SPIN_MAX 32768                     // ~30ms; converts protocol bug into visible
                                           // wrong-answer instead of a hung container

typedef __attribute__((ext_vector_type(8))) short  bf16x8;
typedef __attribute__((ext_vector_type(4))) float  floatx4;
typedef __attribute__((ext_vector_type(4))) int    int4v;

static __device__ __forceinline__ unsigned short bf16_rne(float f) {
    unsigned int u = __float_as_uint(f);
    u += 0x7FFF + ((u >> 16) & 1);
    return (unsigned short)(u >> 16);
}
static __device__ __forceinline__ float sigmoidf_(float x) { return 1.0f / (1.0f + __expf(-x)); }
// fast tanh: exact +/-1 saturation, no NaN for finite x; |err| ~1e-7 << bf16
// rounding (R11-proven on this problem).
static __device__ __forceinline__ float tanhf_fast(float x) {
    return 1.0f - 2.0f / (__expf(2.0f * x) + 1.0f);
}

// write-through stores: land at the device coherence point, leave no dirty L2
// line behind => no buffer_wbl2 needed anywhere in the loop (R0-proven).
static __device__ __forceinline__ void store16_wt(void* p, int4v v) {
    asm volatile("global_store_dwordx4 %0, %1, off sc0 sc1" :: "v"(p), "v"(v) : "memory");
}
static __device__ __forceinline__ void store4_wt(void* p, float v) {
    asm volatile("global_store_dword %0, %1, off sc0 sc1" :: "v"(p), "v"(v) : "memory");
}
static __device__ __forceinline__ void storeu4_wt(void* p, unsigned int v) {
    asm volatile("global_store_dword %0, %1, off sc0 sc1" :: "v"(p), "v"(v) : "memory");
}
// coherence-point loads (bypass L1+L2): always fresh, no acquire-inv needed.
static __device__ __forceinline__ int4v load16_nc(const void* p) {
    int4v v;   // no internal waitcnt — caller fences
    asm volatile("global_load_dwordx4 %0, %1, off sc0 sc1" : "=v"(v) : "v"(p) : "memory");
    return v;
}
static __device__ __forceinline__ float load4_nc(const void* p) {
    float v;   // no internal waitcnt — drained by the next poll fence
    asm volatile("global_load_dword %0, %1, off sc0 sc1" : "=v"(v) : "v"(p) : "memory");
    return v;
}
static __device__ __forceinline__ float load4_ncw(const void* p) {
    float v;
    asm volatile("global_load_dword %0, %1, off sc0 sc1\n\ts_waitcnt vmcnt(0)"
                 : "=v"(v) : "v"(p) : "memory");
    return v;
}
// a 16B chunk is valid iff no dword equals the poison pair. Producers write
// dword-paired values (single dword stores = atomic), so a dword is either
// full-poison or full-data — never torn.
static __device__ __forceinline__ int clean4(int4v c) {
    return (c[0] != (int)POISON) & (c[1] != (int)POISON) &
           (c[2] != (int)POISON) & (c[3] != (int)POISON);
}

// Persistent LSTM decoder. 8 groups x 32 blocks (static grouping). Group g owns
// batches [16g,16g+16); block rb owns dims [32rb,32rb+32) => 128 gate rows
// (8 n-tiles). W' = W_hh + W_ih[:,0](x)W_lin, hi-bf16, in registers. Wave w
// owns K-eighth [128w,128w+128) and ALL 8 n-tiles.
//
// R12 == R11 (proven: flagless data-polling, depth-4 h ring, poison sentinel,
// pre-issued pbuf read, raw barrier, fast tanh) + two deltas:
//  - ONE BARRIER PER STEP via DOUBLE-BUFFERED Dlds[2] (pad 20->18, 147.5KB):
//    B(t) writes Dlds[t&1], C(t) reads Dlds[t&1]; B(t+2)'s rewrite of that
//    buffer is separated from every wave's C(t) reads by the post-B barrier
//    of step t+1. The post-C barrier is DELETED — waves flow from phase C
//    straight into the next poll, so per-wave skew overlaps poll retries
//    instead of serializing at a second rendezvous. Bank math (16-lane
//    phase): pad-18 start offsets 18*l15 mod 32 cover all 16 even residues
//    -> <=2-way -> free (m136). All protocol certificates are per-wave
//    program-order + poll-vmcnt arguments — unaffected by barrier removal
//    (poison still sits after the post-B all-32 merge in program order).
//  - PUBLISH-FIRST in phase C (R8's third delta, now isolated): h publish
//    issues before the poison re-arm + pbuf stores (independent addresses;
//    certificates order them only via the next poll's vmcnt drain).
__global__ __launch_bounds__(NTHR, 2) void decoder_kernel(
    const float* __restrict__ hidden0, const float* __restrict__ cell0,
    const float* __restrict__ Wih,     const float* __restrict__ Whh,
    const float* __restrict__ bih,     const float* __restrict__ bhh,
    const float* __restrict__ Wlin,    const float* __restrict__ blin,
    float* __restrict__ out,           float* __restrict__ ws)
{
    __shared__ __align__(16) float Dlds[2][8][8][16][18];   // 147.5 KB, dbuf
    __shared__ float s0_lds[MPG];

    const int blk  = blockIdx.x;
    const int g    = blk >> 5;          // group 0..7
    const int rb   = blk & 31;          // block in group 0..31
    const int tid  = threadIdx.x;
    const int lane = tid & 63;
    const int wave = tid >> 6;          // 8 waves: wave = K-eighth
    const int l15  = lane & 15;
    const int q    = lane >> 4;

    // ws: flags 8 groups x 64 uints | h ring 1MB (4 slots) | pbuf ring 128 KB
    unsigned int*   flags = (unsigned int*)ws + g * 64;            // 32 used
    unsigned short* hbuf  = (unsigned short*)((char*)ws + 4096);   // [4][G][GRP_SHORTS]
    float*          pbuf  = (float*)((char*)ws + 4096
                             + (size_t)HSLOTS * GRP_STRIDE * 2);   // [4][G][MPG][64]

    // ---- W' hi-bf16 B-fragments in registers: 8 n-tiles x K/8 = 32 frags ----
    bf16x8 w_hi[8][4];
    #pragma unroll
    for (int ntl = 0; ntl < 8; ++ntl) {
        const int gate = ntl >> 1;
        const int row  = gate * H + rb * DPB + (ntl & 1) * 16 + l15;
        const float* wrow  = Whh + (size_t)row * H;
        const float  wih0r = Wih[row * 2];
        #pragma unroll
        for (int kt = 0; kt < 4; ++kt) {
            const int k0 = wave * 128 + kt * 32 + q * 8;
            #pragma unroll
            for (int j = 0; j < 8; ++j) {
                float w = wrow[k0 + j] + wih0r * Wlin[k0 + j];
                w_hi[ntl][kt][j] = (short)bf16_rne(w);
            }
        }
    }

    // ---- pointwise-thread constants (R5 mapping): pm=bq*4+q, pj=nhi*16+l15 ----
    const int bq    = wave >> 1;              // batch quad 0..3
    const int nhi   = wave & 1;               // dim half 0..1
    const int pm    = bq * 4 + q;             // batch in group 0..15
    const int pj    = nhi * 16 + l15;         // dim within block 0..31
    const int bglob = g * MPG + pm;
    const int kdim  = rb * DPB + pj;
    const float bl  = blin[0];
    float bias_p[4], bias0_p[4], wih0_p[4];
    #pragma unroll
    for (int gt = 0; gt < 4; ++gt) {
        int r2 = gt * H + kdim;
        float b0 = bih[r2] + bhh[r2];
        float w0 = Wih[r2 * 2];
        bias0_p[gt] = b0;
        wih0_p[gt]  = w0;
        bias_p[gt]  = b0 + Wih[r2 * 2 + 1] + w0 * bl;   // folded bias (t>=1)
    }
    float cstate = cell0[(size_t)bglob * H + kdim];
    const float wlin_p = Wlin[kdim];

    // h addressing: chunk layout short index within a (slot,group) region
    const size_t hoff = (size_t)rb * 512 + (pj >> 3) * 128 + pm * 8 + (pj & 7);
    unsigned short* hgrp   = hbuf + (size_t)g * GRP_SHORTS;    // slot 0 of my group
    unsigned short* hpairb = hgrp + hoff;                      // my pair addr (even lanes)
    unsigned short* mychk  = hgrp + (size_t)rb * 512;          // my 1KB chunk, slot 0

    const int4v pois = { (int)POISON, (int)POISON, (int)POISON, (int)POISON };

    // ---- preamble: poison own chunk in ALL 4 slots (before any h0 publish) ----
    if (lane < 8) {
        #pragma unroll
        for (int s = 0; s < HSLOTS; ++s)
            store16_wt((char*)(mychk + (size_t)s * GRP_STRIDE) + wave * 128 + lane * 16,
                       pois);
    }

    // ---- s0[m] = Wlin . h0[m]  (t=0 rank-1 correction; old thread mapping) ----
    {
        const int pm_o = tid >> 5, pj_o = tid & 31;
        const float* hp = hidden0 + (size_t)(g * MPG + pm_o) * H + pj_o * 32;
        const float* wp = Wlin + pj_o * 32;
        float s = 0.f;
        #pragma unroll 4
        for (int kk = 0; kk < 32; kk += 4) {
            float4 hv = *(const float4*)(hp + kk);
            float4 wv = *(const float4*)(wp + kk);
            s += hv.x * wv.x + hv.y * wv.y + hv.z * wv.z + hv.w * wv.w;
        }
        s += __shfl_xor(s, 1); s += __shfl_xor(s, 2);
        s += __shfl_xor(s, 4); s += __shfl_xor(s, 8); s += __shfl_xor(s, 16);
        if (pj_o == 0) s0_lds[pm_o] = s;
    }

    // one-time flag round: all poisons committed before ANY h0 store issues
    asm volatile("s_waitcnt vmcnt(0)" ::: "memory");
    __syncthreads();
    if (tid == 0)
        __hip_atomic_store(&flags[rb], 1u, __ATOMIC_RELAXED, __HIP_MEMORY_SCOPE_AGENT);
    if (wave == 0) {
        for (int spin = 0; spin < SPIN_MAX; ++spin) {
            unsigned int v = __hip_atomic_load(&flags[lane & 31], __ATOMIC_RELAXED,
                                               __HIP_MEMORY_SCOPE_AGENT);
            if (__all((int)(v >= 1u))) break;
        }
    }
    __syncthreads();

    // ---- h0 publish into slot 0: paired-dword, fire-and-forget ----
    {
        float v0 = hidden0[(size_t)bglob * H + kdim];
        unsigned int hs = bf16_rne(v0);
        unsigned int pw = (unsigned int)__shfl_xor((int)hs, 1);
        if (!(lane & 1))
            storeu4_wt(hpairb, (hs & 0xFFFFu) | (pw << 16));
    }

    float pv = 0.f;   // pre-issued pbuf partial (wave1), drained by poll fence

    for (int t = 0; t < T; ++t) {
        // ---- phase A: DATA-POLL this wave's 4 chunks of slot t&3 ----
        const char* hsrc = (const char*)(hgrp + (size_t)(t & 3) * GRP_STRIDE)
                         + wave * 4096 + lane * 16;
        int4v a0, a1, a2, a3;
        for (int spin = 0; spin < SPIN_MAX; ++spin) {
            a0 = load16_nc(hsrc);
            a1 = load16_nc(hsrc + 1024);
            a2 = load16_nc(hsrc + 2048);
            a3 = load16_nc(hsrc + 3072);
            // drain point: commits all of MY prior stores (publish/poison/pbuf)
            // and completes these loads + the pre-issued pv load
            asm volatile("s_waitcnt vmcnt(0)"
                         : "+v"(a0), "+v"(a1), "+v"(a2), "+v"(a3), "+v"(pv));
            if (__all(clean4(a0) & clean4(a1) & clean4(a2) & clean4(a3))) break;
        }
        if (wave == 1 && rb < MPG && t >= 3) {
            // batch m = rb: step t-3's 64 partials (pre-issued last phase C)
            float v = pv;
            v += __shfl_xor(v, 1); v += __shfl_xor(v, 2); v += __shfl_xor(v, 4);
            v += __shfl_xor(v, 8); v += __shfl_xor(v, 16); v += __shfl_xor(v, 32);
            if (lane == 0) out[(size_t)(g * MPG + rb) * T + (t - 3)] = v + bl;
        }

        // ---- phase B: MFMA. wave w: 8 n-tiles x 16 batches x K/8 ----
        bf16x8 a[4];
        a[0] = __builtin_bit_cast(bf16x8, a0);
        a[1] = __builtin_bit_cast(bf16x8, a1);
        a[2] = __builtin_bit_cast(bf16x8, a2);
        a[3] = __builtin_bit_cast(bf16x8, a3);
        floatx4 acc[8];
        #pragma unroll
        for (int ntl = 0; ntl < 8; ++ntl) acc[ntl] = (floatx4){0.f, 0.f, 0.f, 0.f};
        #pragma unroll
        for (int kt = 0; kt < 4; ++kt) {
            #pragma unroll
            for (int ntl = 0; ntl < 8; ++ntl)
                acc[ntl] = __builtin_amdgcn_mfma_f32_16x16x32_bf16(a[kt], w_hi[ntl][kt], acc[ntl], 0, 0, 0);
        }
        #pragma unroll
        for (int ntl = 0; ntl < 8; ++ntl)
            *(floatx4*)&Dlds[t & 1][wave][ntl][l15][q * 4] = acc[ntl];

        // ---- the ONLY barrier per step: Dlds[t&1] writes visible to readers.
        //      vmcnt is already 0 here (phase-A poll drained everything), so a
        //      raw lgkmcnt-only barrier loses nothing and waits for nothing
        //      but LDS. ----
        asm volatile("s_waitcnt lgkmcnt(0)" ::: "memory");
        __builtin_amdgcn_s_barrier();
        __builtin_amdgcn_sched_barrier(0);

        // ---- phase C (publish-first; no trailing barrier — flow into t+1) ----
        {
            // b128 kk-sum: gate q's chain for dims pj, batches bq*4..+3
            const float* rbase = &Dlds[t & 1][0][q * 2 + nhi][l15][bq * 4];
            floatx4 S = *(const floatx4*)rbase;
            #pragma unroll
            for (int kk = 1; kk < 8; ++kk)
                S = S + *(const floatx4*)(rbase + kk * 2304);   // kk stride 8*16*18

            // 4x4 transpose across lane quads: gg[i] = gate i, batch bq*4+q
            float a4[4] = {S[0], S[1], S[2], S[3]};
            float cc[4], gg[4];
            #pragma unroll
            for (int j = 0; j < 4; ++j) {
                float tv = __shfl_xor(a4[j ^ 1], 16);
                cc[j] = ((j ^ q) & 1) ? tv : a4[j];
            }
            #pragma unroll
            for (int j = 0; j < 4; ++j) {
                float tv = __shfl_xor(cc[j ^ 2], 32);
                gg[j] = ((j ^ q) & 2) ? tv : cc[j];
            }

            float gv[4];
            if (t == 0) {
                float s0 = s0_lds[pm];
                #pragma unroll
                for (int gt = 0; gt < 4; ++gt) gv[gt] = gg[gt] + bias0_p[gt] - wih0_p[gt] * s0;
            } else {
                #pragma unroll
                for (int gt = 0; gt < 4; ++gt) gv[gt] = gg[gt] + bias_p[gt];
            }
            float ig  = sigmoidf_(gv[0]);
            float fg  = sigmoidf_(gv[1]);
            float gt_ = tanhf_fast(gv[2]);
            float og  = sigmoidf_(gv[3]);
            cstate = fg * cstate + ig * gt_;
            float hnew = og * tanhf_fast(cstate);

            // 1) h publish into slot (t+1)&3 FIRST (critical message heads the
            //    store queue); paired-dword, fire-and-forget
            unsigned int hs = bf16_rne(hnew);
            unsigned int pw = (unsigned int)__shfl_xor((int)hs, 1);
            if (!(lane & 1))
                storeu4_wt(hpairb + (size_t)((t + 1) & 3) * GRP_STRIDE,
                           (hs & 0xFFFFu) | (pw << 16));

            // 2) poison re-arm: slot (t+3)&3 == (t-1)&3 (peers' reads of it are
            //    certified complete by the post-B all-32 merge this step)
            if (lane < 8)
                store16_wt((char*)(mychk + (size_t)((t + 3) & 3) * GRP_STRIDE)
                           + wave * 128 + lane * 16, pois);

            // 3) po partial per (batch, dim-half): reduce over 16 dim lanes
            float po = wlin_p * hnew;
            po += __shfl_xor(po, 1); po += __shfl_xor(po, 2);
            po += __shfl_xor(po, 4); po += __shfl_xor(po, 8);
            if (l15 == 0)
                store4_wt(pbuf + (size_t)(((t & 3) * GROUPS + g) * MPG + pm) * 64
                          + nhi * 32 + rb, po);
        }

        // ---- pre-issue step t+1's pbuf read (wave1; slot (t-2)&3, certified
        //      committed by this step's post-B all-32 merge) — R9-proven ----
        if (wave == 1 && rb < MPG && t >= 2 && t < T - 1) {
            const float* pr = pbuf + (size_t)((((t - 2) & 3) * GROUPS + g) * MPG + rb) * 64;
            pv = load4_nc(pr + lane);
        }
        // no post-C barrier: Dlds double-buffer makes next step's B writes safe
        // (B(t+1) targets Dlds[(t+1)&1]; B(t+2)'s reuse of Dlds[t&1] sits
        // behind the post-B barrier of t+1, which follows every wave's C(t))
    }

    // ---- epilogue: one flag round orders final pbuf commits, then T-3..T-1 ----
    asm volatile("s_waitcnt vmcnt(0)" ::: "memory");
    __syncthreads();
    if (tid == 0)
        __hip_atomic_store(&flags[rb], 2u, __ATOMIC_RELAXED, __HIP_MEMORY_SCOPE_AGENT);
    if (wave == 1 && rb < MPG) {
        for (int spin = 0; spin < SPIN_MAX; ++spin) {
            unsigned int v = __hip_atomic_load(&flags[lane & 31], __ATOMIC_RELAXED,
                                               __HIP_MEMORY_SCOPE_AGENT);
            if (__all((int)(v >= 2u))) break;
        }
        for (int tt = T - 3; tt < T; ++tt) {
            const float* pr = pbuf + (size_t)(((tt & 3) * GROUPS + g) * MPG + rb) * 64;
            float v = load4_ncw(pr + lane);
            v += __shfl_xor(v, 1); v += __shfl_xor(v, 2); v += __shfl_xor(v, 4);
            v += __shfl_xor(v, 8); v += __shfl_xor(v, 16); v += __shfl_xor(v, 32);
            if (lane == 0) out[(size_t)(g * MPG + rb) * T + tt] = v + bl;
        }
    }
}

extern "C" void kernel_launch(void* const* d_in, const int* in_sizes, int n_in,
                              void* d_out, int out_size, void* d_ws, size_t ws_size,
                              hipStream_t stream) {
    const float* hidden0 = (const float*)d_in[0];
    const float* cell0   = (const float*)d_in[1];
    const float* Wih     = (const float*)d_in[2];
    const float* Whh     = (const float*)d_in[3];
    const float* bih     = (const float*)d_in[4];
    const float* bhh     = (const float*)d_in[5];
    const float* Wlin    = (const float*)d_in[6];
    const float* blin    = (const float*)d_in[7];
    float* out = (float*)d_out;
    float* ws  = (float*)d_ws;

    // zero the preamble/epilogue flags
    hipMemsetAsync(d_ws, 0, 4096, stream);

    void* args[] = { &hidden0, &cell0, &Wih, &Whh, &bih, &bhh, &Wlin, &blin,
                     &out, &ws };
    hipLaunchCooperativeKernel((const void*)decoder_kernel,
                               dim3(GROUPS * BPG), dim3(NTHR), args, 0, stream);
}

// Round 13
// 955.180 us; speedup vs baseline: 1.6268x; 1.6268x over previous
//
#include <hip/hip_runtime.h>
#include <math.h>

#define H      1024
#define B      128
#define T      256
#define GROUPS 8        // 8 groups x 32 blocks = 256 blocks (1/CU target)
#define BPG    32       // blocks per group; block owns 32 dims = 128 gate rows
#define NTHR   512
#define MPG    16       // batches per group
#define DPB    32       // dims per block
#define GRP_SHORTS (MPG * H)               // 16384 shorts = 32KB per group per slot
#define GRP_STRIDE (GROUPS * GRP_SHORTS)   // shorts per h-ring slot (all groups)
#define HSLOTS 4
#define POISON 0x7F807F80u                 // bf16 +inf pair: unreachable by h=og*tanh(c)
#define SPIN_MAX 32768                     // ~30ms; converts protocol bug into visible
                                           // wrong-answer instead of a hung container

typedef __attribute__((ext_vector_type(8))) short  bf16x8;
typedef __attribute__((ext_vector_type(4))) float  floatx4;
typedef __attribute__((ext_vector_type(4))) int    int4v;

static __device__ __forceinline__ unsigned short bf16_rne(float f) {
    unsigned int u = __float_as_uint(f);
    u += 0x7FFF + ((u >> 16) & 1);
    return (unsigned short)(u >> 16);
}
static __device__ __forceinline__ float sigmoidf_(float x) { return 1.0f / (1.0f + __expf(-x)); }
// fast tanh: exact +/-1 saturation, no NaN for finite x; |err| ~1e-7 << bf16
// rounding (R11-proven on this problem).
static __device__ __forceinline__ float tanhf_fast(float x) {
    return 1.0f - 2.0f / (__expf(2.0f * x) + 1.0f);
}

// write-through stores: land at the device coherence point, leave no dirty L2
// line behind => no buffer_wbl2 needed anywhere in the loop (R0-proven).
static __device__ __forceinline__ void store16_wt(void* p, int4v v) {
    asm volatile("global_store_dwordx4 %0, %1, off sc0 sc1" :: "v"(p), "v"(v) : "memory");
}
static __device__ __forceinline__ void store4_wt(void* p, float v) {
    asm volatile("global_store_dword %0, %1, off sc0 sc1" :: "v"(p), "v"(v) : "memory");
}
static __device__ __forceinline__ void storeu4_wt(void* p, unsigned int v) {
    asm volatile("global_store_dword %0, %1, off sc0 sc1" :: "v"(p), "v"(v) : "memory");
}
// coherence-point loads (bypass L1+L2): always fresh, no acquire-inv needed.
static __device__ __forceinline__ int4v load16_nc(const void* p) {
    int4v v;   // no internal waitcnt — caller fences
    asm volatile("global_load_dwordx4 %0, %1, off sc0 sc1" : "=v"(v) : "v"(p) : "memory");
    return v;
}
static __device__ __forceinline__ float load4_nc(const void* p) {
    float v;   // no internal waitcnt — drained by the next poll fence
    asm volatile("global_load_dword %0, %1, off sc0 sc1" : "=v"(v) : "v"(p) : "memory");
    return v;
}
static __device__ __forceinline__ float load4_ncw(const void* p) {
    float v;
    asm volatile("global_load_dword %0, %1, off sc0 sc1\n\ts_waitcnt vmcnt(0)"
                 : "=v"(v) : "v"(p) : "memory");
    return v;
}
// a 16B chunk is valid iff no dword equals the poison pair. Producers write
// dword-paired values (single dword stores = atomic), so a dword is either
// full-poison or full-data — never torn.
static __device__ __forceinline__ int clean4(int4v c) {
    return (c[0] != (int)POISON) & (c[1] != (int)POISON) &
           (c[2] != (int)POISON) & (c[3] != (int)POISON);
}

// Persistent LSTM decoder. 8 groups x 32 blocks (static grouping). Group g owns
// batches [16g,16g+16); block rb owns dims [32rb,32rb+32) => 128 gate rows
// (8 n-tiles). W' = W_hh + W_ih[:,0](x)W_lin, hi-bf16, in registers. Wave w
// owns K-eighth [128w,128w+128) and ALL 8 n-tiles.
//
// R13 == R11 (proven best: flagless data-polling, depth-4 h ring, poison
// sentinel, pre-issued pbuf read, raw post-C barrier, fast tanh, TWO barriers
// per step — R12 proved the post-C rendezvous bounds the poll window and
// keeps the group phase-locked; removing it regressed 70%) + ONE delta:
//  - PUBLISH-FIRST in phase C (isolated test; never cleanly measured):
//    order = compute -> h publish -> poison re-arm -> pbuf. R11 issued the 8
//    poison stores at the TOP of phase C, queued ahead of the critical h
//    publish. Poison's only deadline is the next poll's vmcnt fence (a full
//    phase of margin), so delaying its issue is certificate-neutral.
__global__ __launch_bounds__(NTHR, 2) void decoder_kernel(
    const float* __restrict__ hidden0, const float* __restrict__ cell0,
    const float* __restrict__ Wih,     const float* __restrict__ Whh,
    const float* __restrict__ bih,     const float* __restrict__ bhh,
    const float* __restrict__ Wlin,    const float* __restrict__ blin,
    float* __restrict__ out,           float* __restrict__ ws)
{
    __shared__ __align__(16) float Dlds[8][8][16][20];   // 80 KB: [kk][ntl][n][m+pad4]
    __shared__ float s0_lds[MPG];

    const int blk  = blockIdx.x;
    const int g    = blk >> 5;          // group 0..7
    const int rb   = blk & 31;          // block in group 0..31
    const int tid  = threadIdx.x;
    const int lane = tid & 63;
    const int wave = tid >> 6;          // 8 waves: wave = K-eighth
    const int l15  = lane & 15;
    const int q    = lane >> 4;

    // ws: flags 8 groups x 64 uints | h ring 1MB (4 slots) | pbuf ring 128 KB
    unsigned int*   flags = (unsigned int*)ws + g * 64;            // 32 used
    unsigned short* hbuf  = (unsigned short*)((char*)ws + 4096);   // [4][G][GRP_SHORTS]
    float*          pbuf  = (float*)((char*)ws + 4096
                             + (size_t)HSLOTS * GRP_STRIDE * 2);   // [4][G][MPG][64]

    // ---- W' hi-bf16 B-fragments in registers: 8 n-tiles x K/8 = 32 frags ----
    bf16x8 w_hi[8][4];
    #pragma unroll
    for (int ntl = 0; ntl < 8; ++ntl) {
        const int gate = ntl >> 1;
        const int row  = gate * H + rb * DPB + (ntl & 1) * 16 + l15;
        const float* wrow  = Whh + (size_t)row * H;
        const float  wih0r = Wih[row * 2];
        #pragma unroll
        for (int kt = 0; kt < 4; ++kt) {
            const int k0 = wave * 128 + kt * 32 + q * 8;
            #pragma unroll
            for (int j = 0; j < 8; ++j) {
                float w = wrow[k0 + j] + wih0r * Wlin[k0 + j];
                w_hi[ntl][kt][j] = (short)bf16_rne(w);
            }
        }
    }

    // ---- pointwise-thread constants (R5 mapping): pm=bq*4+q, pj=nhi*16+l15 ----
    const int bq    = wave >> 1;              // batch quad 0..3
    const int nhi   = wave & 1;               // dim half 0..1
    const int pm    = bq * 4 + q;             // batch in group 0..15
    const int pj    = nhi * 16 + l15;         // dim within block 0..31
    const int bglob = g * MPG + pm;
    const int kdim  = rb * DPB + pj;
    const float bl  = blin[0];
    float bias_p[4], bias0_p[4], wih0_p[4];
    #pragma unroll
    for (int gt = 0; gt < 4; ++gt) {
        int r2 = gt * H + kdim;
        float b0 = bih[r2] + bhh[r2];
        float w0 = Wih[r2 * 2];
        bias0_p[gt] = b0;
        wih0_p[gt]  = w0;
        bias_p[gt]  = b0 + Wih[r2 * 2 + 1] + w0 * bl;   // folded bias (t>=1)
    }
    float cstate = cell0[(size_t)bglob * H + kdim];
    const float wlin_p = Wlin[kdim];

    // h addressing: chunk layout short index within a (slot,group) region
    const size_t hoff = (size_t)rb * 512 + (pj >> 3) * 128 + pm * 8 + (pj & 7);
    unsigned short* hgrp   = hbuf + (size_t)g * GRP_SHORTS;    // slot 0 of my group
    unsigned short* hpairb = hgrp + hoff;                      // my pair addr (even lanes)
    unsigned short* mychk  = hgrp + (size_t)rb * 512;          // my 1KB chunk, slot 0

    const int4v pois = { (int)POISON, (int)POISON, (int)POISON, (int)POISON };

    // ---- preamble: poison own chunk in ALL 4 slots (before any h0 publish) ----
    if (lane < 8) {
        #pragma unroll
        for (int s = 0; s < HSLOTS; ++s)
            store16_wt((char*)(mychk + (size_t)s * GRP_STRIDE) + wave * 128 + lane * 16,
                       pois);
    }

    // ---- s0[m] = Wlin . h0[m]  (t=0 rank-1 correction; old thread mapping) ----
    {
        const int pm_o = tid >> 5, pj_o = tid & 31;
        const float* hp = hidden0 + (size_t)(g * MPG + pm_o) * H + pj_o * 32;
        const float* wp = Wlin + pj_o * 32;
        float s = 0.f;
        #pragma unroll 4
        for (int kk = 0; kk < 32; kk += 4) {
            float4 hv = *(const float4*)(hp + kk);
            float4 wv = *(const float4*)(wp + kk);
            s += hv.x * wv.x + hv.y * wv.y + hv.z * wv.z + hv.w * wv.w;
        }
        s += __shfl_xor(s, 1); s += __shfl_xor(s, 2);
        s += __shfl_xor(s, 4); s += __shfl_xor(s, 8); s += __shfl_xor(s, 16);
        if (pj_o == 0) s0_lds[pm_o] = s;
    }

    // one-time flag round: all poisons committed before ANY h0 store issues
    asm volatile("s_waitcnt vmcnt(0)" ::: "memory");
    __syncthreads();
    if (tid == 0)
        __hip_atomic_store(&flags[rb], 1u, __ATOMIC_RELAXED, __HIP_MEMORY_SCOPE_AGENT);
    if (wave == 0) {
        for (int spin = 0; spin < SPIN_MAX; ++spin) {
            unsigned int v = __hip_atomic_load(&flags[lane & 31], __ATOMIC_RELAXED,
                                               __HIP_MEMORY_SCOPE_AGENT);
            if (__all((int)(v >= 1u))) break;
        }
    }
    __syncthreads();

    // ---- h0 publish into slot 0: paired-dword, fire-and-forget ----
    {
        float v0 = hidden0[(size_t)bglob * H + kdim];
        unsigned int hs = bf16_rne(v0);
        unsigned int pw = (unsigned int)__shfl_xor((int)hs, 1);
        if (!(lane & 1))
            storeu4_wt(hpairb, (hs & 0xFFFFu) | (pw << 16));
    }

    float pv = 0.f;   // pre-issued pbuf partial (wave1), drained by poll fence

    for (int t = 0; t < T; ++t) {
        // ---- phase A: DATA-POLL this wave's 4 chunks of slot t&3 ----
        const char* hsrc = (const char*)(hgrp + (size_t)(t & 3) * GRP_STRIDE)
                         + wave * 4096 + lane * 16;
        int4v a0, a1, a2, a3;
        for (int spin = 0; spin < SPIN_MAX; ++spin) {
            a0 = load16_nc(hsrc);
            a1 = load16_nc(hsrc + 1024);
            a2 = load16_nc(hsrc + 2048);
            a3 = load16_nc(hsrc + 3072);
            // drain point: commits all of MY prior stores (publish/poison/pbuf)
            // and completes these loads + the pre-issued pv load
            asm volatile("s_waitcnt vmcnt(0)"
                         : "+v"(a0), "+v"(a1), "+v"(a2), "+v"(a3), "+v"(pv));
            if (__all(clean4(a0) & clean4(a1) & clean4(a2) & clean4(a3))) break;
        }
        if (wave == 1 && rb < MPG && t >= 3) {
            // batch m = rb: step t-3's 64 partials (pre-issued last phase C)
            float v = pv;
            v += __shfl_xor(v, 1); v += __shfl_xor(v, 2); v += __shfl_xor(v, 4);
            v += __shfl_xor(v, 8); v += __shfl_xor(v, 16); v += __shfl_xor(v, 32);
            if (lane == 0) out[(size_t)(g * MPG + rb) * T + (t - 3)] = v + bl;
        }

        // ---- phase B: MFMA. wave w: 8 n-tiles x 16 batches x K/8 ----
        bf16x8 a[4];
        a[0] = __builtin_bit_cast(bf16x8, a0);
        a[1] = __builtin_bit_cast(bf16x8, a1);
        a[2] = __builtin_bit_cast(bf16x8, a2);
        a[3] = __builtin_bit_cast(bf16x8, a3);
        floatx4 acc[8];
        #pragma unroll
        for (int ntl = 0; ntl < 8; ++ntl) acc[ntl] = (floatx4){0.f, 0.f, 0.f, 0.f};
        #pragma unroll
        for (int kt = 0; kt < 4; ++kt) {
            #pragma unroll
            for (int ntl = 0; ntl < 8; ++ntl)
                acc[ntl] = __builtin_amdgcn_mfma_f32_16x16x32_bf16(a[kt], w_hi[ntl][kt], acc[ntl], 0, 0, 0);
        }
        #pragma unroll
        for (int ntl = 0; ntl < 8; ++ntl)
            *(floatx4*)&Dlds[wave][ntl][l15][q * 4] = acc[ntl];
        __syncthreads();   // post-B: Dlds complete (implicit vmcnt ~free here:
                           // phase-A already drained; lgkmcnt covers ds_writes)

        // ---- phase C (R13 order: compute -> PUBLISH -> poison -> pbuf) ----
        {
            // b128 kk-sum: gate q's chain for dims pj, batches bq*4..+3
            const float* rbase = &Dlds[0][q * 2 + nhi][l15][bq * 4];
            floatx4 S = *(const floatx4*)rbase;
            #pragma unroll
            for (int kk = 1; kk < 8; ++kk)
                S = S + *(const floatx4*)(rbase + kk * 2560);   // kk stride 8*16*20

            // 4x4 transpose across lane quads: gg[i] = gate i, batch bq*4+q
            float a4[4] = {S[0], S[1], S[2], S[3]};
            float cc[4], gg[4];
            #pragma unroll
            for (int j = 0; j < 4; ++j) {
                float tv = __shfl_xor(a4[j ^ 1], 16);
                cc[j] = ((j ^ q) & 1) ? tv : a4[j];
            }
            #pragma unroll
            for (int j = 0; j < 4; ++j) {
                float tv = __shfl_xor(cc[j ^ 2], 32);
                gg[j] = ((j ^ q) & 2) ? tv : cc[j];
            }

            float gv[4];
            if (t == 0) {
                float s0 = s0_lds[pm];
                #pragma unroll
                for (int gt = 0; gt < 4; ++gt) gv[gt] = gg[gt] + bias0_p[gt] - wih0_p[gt] * s0;
            } else {
                #pragma unroll
                for (int gt = 0; gt < 4; ++gt) gv[gt] = gg[gt] + bias_p[gt];
            }
            float ig  = sigmoidf_(gv[0]);
            float fg  = sigmoidf_(gv[1]);
            float gt_ = tanhf_fast(gv[2]);
            float og  = sigmoidf_(gv[3]);
            cstate = fg * cstate + ig * gt_;
            float hnew = og * tanhf_fast(cstate);

            // 1) h publish into slot (t+1)&3 FIRST (critical message heads the
            //    store queue); paired-dword (atomic, never torn), fire-and-forget
            unsigned int hs = bf16_rne(hnew);
            unsigned int pw = (unsigned int)__shfl_xor((int)hs, 1);
            if (!(lane & 1))
                storeu4_wt(hpairb + (size_t)((t + 1) & 3) * GRP_STRIDE,
                           (hs & 0xFFFFu) | (pw << 16));

            // 2) poison re-arm: slot (t+3)&3 == (t-1)&3 (peers' reads of it are
            //    certified complete by the post-B all-32 merge this step);
            //    deadline = next poll fence, a full phase away
            if (lane < 8)
                store16_wt((char*)(mychk + (size_t)((t + 3) & 3) * GRP_STRIDE)
                           + wave * 128 + lane * 16, pois);

            // 3) po partial per (batch, dim-half): reduce over 16 dim lanes
            float po = wlin_p * hnew;
            po += __shfl_xor(po, 1); po += __shfl_xor(po, 2);
            po += __shfl_xor(po, 4); po += __shfl_xor(po, 8);
            if (l15 == 0)
                store4_wt(pbuf + (size_t)(((t & 3) * GROUPS + g) * MPG + pm) * 64
                          + nhi * 32 + rb, po);
        }

        // ---- pre-issue step t+1's pbuf read (wave1; slot (t-2)&3, certified
        //      committed by this step's post-B all-32 merge) — R9-proven ----
        if (wave == 1 && rb < MPG && t >= 2 && t < T - 1) {
            const float* pr = pbuf + (size_t)((((t - 2) & 3) * GROUPS + g) * MPG + rb) * 64;
            pv = load4_nc(pr + lane);
        }

        // ---- post-C sync: RAW barrier — LDS ordering + poll-window bounding
        //      (R12 proved this rendezvous is load-bearing for performance).
        //      WT stores stay in flight; they ack during the next poll RTT. ----
        asm volatile("s_waitcnt lgkmcnt(0)" ::: "memory");
        __builtin_amdgcn_s_barrier();
        __builtin_amdgcn_sched_barrier(0);
    }

    // ---- epilogue: one flag round orders final pbuf commits, then T-3..T-1 ----
    asm volatile("s_waitcnt vmcnt(0)" ::: "memory");
    __syncthreads();
    if (tid == 0)
        __hip_atomic_store(&flags[rb], 2u, __ATOMIC_RELAXED, __HIP_MEMORY_SCOPE_AGENT);
    if (wave == 1 && rb < MPG) {
        for (int spin = 0; spin < SPIN_MAX; ++spin) {
            unsigned int v = __hip_atomic_load(&flags[lane & 31], __ATOMIC_RELAXED,
                                               __HIP_MEMORY_SCOPE_AGENT);
            if (__all((int)(v >= 2u))) break;
        }
        for (int tt = T - 3; tt < T; ++tt) {
            const float* pr = pbuf + (size_t)(((tt & 3) * GROUPS + g) * MPG + rb) * 64;
            float v = load4_ncw(pr + lane);
            v += __shfl_xor(v, 1); v += __shfl_xor(v, 2); v += __shfl_xor(v, 4);
            v += __shfl_xor(v, 8); v += __shfl_xor(v, 16); v += __shfl_xor(v, 32);
            if (lane == 0) out[(size_t)(g * MPG + rb) * T + tt] = v + bl;
        }
    }
}

extern "C" void kernel_launch(void* const* d_in, const int* in_sizes, int n_in,
                              void* d_out, int out_size, void* d_ws, size_t ws_size,
                              hipStream_t stream) {
    const float* hidden0 = (const float*)d_in[0];
    const float* cell0   = (const float*)d_in[1];
    const float* Wih     = (const float*)d_in[2];
    const float* Whh     = (const float*)d_in[3];
    const float* bih     = (const float*)d_in[4];
    const float* bhh     = (const float*)d_in[5];
    const float* Wlin    = (const float*)d_in[6];
    const float* blin    = (const float*)d_in[7];
    float* out = (float*)d_out;
    float* ws  = (float*)d_ws;

    // zero the preamble/epilogue flags
    hipMemsetAsync(d_ws, 0, 4096, stream);

    void* args[] = { &hidden0, &cell0, &Wih, &Whh, &bih, &bhh, &Wlin, &blin,
                     &out, &ws };
    hipLaunchCooperativeKernel((const void*)decoder_kernel,
                               dim3(GROUPS * BPG), dim3(NTHR), args, 0, stream);
}

// Round 14
// 938.099 us; speedup vs baseline: 1.6564x; 1.0182x over previous
//
#include <hip/hip_runtime.h>
#include <math.h>

#define H      1024
#define B      128
#define T      256
#define GROUPS 8        // 8 groups x 32 blocks = 256 blocks (1/CU target)
#define BPG    32       // blocks per group; block owns 32 dims = 128 gate rows
#define NTHR   512
#define MPG    16       // batches per group
#define DPB    32       // dims per block
#define GRP_SHORTS (MPG * H)               // 16384 shorts = 32KB per group per slot
#define GRP_STRIDE (GROUPS * GRP_SHORTS)   // shorts per h-ring slot (all groups)
#define HSLOTS 4
#define POISON 0x7F807F80u                 // bf16 +inf pair: unreachable by h=og*tanh(c)
#define SPIN_MAX 32768                     // ~30ms; converts protocol bug into visible
                                           // wrong-answer instead of a hung container

typedef __attribute__((ext_vector_type(8))) short  bf16x8;
typedef __attribute__((ext_vector_type(4))) float  floatx4;
typedef __attribute__((ext_vector_type(4))) int    int4v;

static __device__ __forceinline__ unsigned short bf16_rne(float f) {
    unsigned int u = __float_as_uint(f);
    u += 0x7FFF + ((u >> 16) & 1);
    return (unsigned short)(u >> 16);
}
static __device__ __forceinline__ float sigmoidf_(float x) { return 1.0f / (1.0f + __expf(-x)); }
// fast tanh: exact +/-1 saturation, no NaN for finite x; |err| ~1e-7 << bf16
// rounding (R11-proven on this problem).
static __device__ __forceinline__ float tanhf_fast(float x) {
    return 1.0f - 2.0f / (__expf(2.0f * x) + 1.0f);
}

// write-through stores: land at the device coherence point, leave no dirty L2
// line behind => no buffer_wbl2 needed anywhere in the loop (R0-proven).
static __device__ __forceinline__ void store16_wt(void* p, int4v v) {
    asm volatile("global_store_dwordx4 %0, %1, off sc0 sc1" :: "v"(p), "v"(v) : "memory");
}
static __device__ __forceinline__ void store4_wt(void* p, float v) {
    asm volatile("global_store_dword %0, %1, off sc0 sc1" :: "v"(p), "v"(v) : "memory");
}
static __device__ __forceinline__ void storeu4_wt(void* p, unsigned int v) {
    asm volatile("global_store_dword %0, %1, off sc0 sc1" :: "v"(p), "v"(v) : "memory");
}
// coherence-point loads (bypass L1+L2): always fresh, no acquire-inv needed.
static __device__ __forceinline__ int4v load16_nc(const void* p) {
    int4v v;   // no internal waitcnt — caller fences
    asm volatile("global_load_dwordx4 %0, %1, off sc0 sc1" : "=v"(v) : "v"(p) : "memory");
    return v;
}
static __device__ __forceinline__ float load4_nc(const void* p) {
    float v;   // no internal waitcnt — drained by the next poll fence
    asm volatile("global_load_dword %0, %1, off sc0 sc1" : "=v"(v) : "v"(p) : "memory");
    return v;
}
static __device__ __forceinline__ float load4_ncw(const void* p) {
    float v;
    asm volatile("global_load_dword %0, %1, off sc0 sc1\n\ts_waitcnt vmcnt(0)"
                 : "=v"(v) : "v"(p) : "memory");
    return v;
}
// a 16B chunk is valid iff no dword equals the poison pair. Producers write
// dword-paired values (single dword stores = atomic), so a dword is either
// full-poison or full-data — never torn.
static __device__ __forceinline__ int clean4(int4v c) {
    return (c[0] != (int)POISON) & (c[1] != (int)POISON) &
           (c[2] != (int)POISON) & (c[3] != (int)POISON);
}

// Persistent LSTM decoder. 8 groups x 32 blocks (static grouping). Group g owns
// batches [16g,16g+16); block rb owns dims [32rb,32rb+32) => 128 gate rows
// (8 n-tiles). W' = W_hh + W_ih[:,0](x)W_lin, hi-bf16, in registers. Wave w
// owns K-eighth [128w,128w+128) and ALL 8 n-tiles.
//
// R14 == R11 EXACT REVERT — the proven optimum of this protocol family.
// Search-tree verdicts (all isolated, hardware-measured):
//  - data-polling ring + poison sentinel: 1092 -> 1000 us steady (R7)
//  - pre-issued pbuf read (wave1): 1000 -> 926 (R9)
//  - raw post-C barrier + fast tanh: 926 -> 875 (R11)   <- THIS KERNEL
//  - pre-issued h-polls: NaN twice (R8, R10) — RETIRED
//  - single-barrier + Dlds dbuf: 875 -> 1480 (R12) — post-C rendezvous is
//    load-bearing (bounds poll window, phase-locks the group) — RETIRED
//  - publish-first phase C: 875 -> 899 (R13) — poison-first wins — RETIRED
// Remaining time = 256 strictly-serial steps x (publish-commit + observe RTT
// + 2 rendezvous + compute) at device-coherence-point latency; no throughput
// counter is near roof (MfmaUtil ~13%, HBM ~10%) — latency-bound by design
// of the dependence chain.
__global__ __launch_bounds__(NTHR, 2) void decoder_kernel(
    const float* __restrict__ hidden0, const float* __restrict__ cell0,
    const float* __restrict__ Wih,     const float* __restrict__ Whh,
    const float* __restrict__ bih,     const float* __restrict__ bhh,
    const float* __restrict__ Wlin,    const float* __restrict__ blin,
    float* __restrict__ out,           float* __restrict__ ws)
{
    __shared__ __align__(16) float Dlds[8][8][16][20];   // 80 KB: [kk][ntl][n][m+pad4]
    __shared__ float s0_lds[MPG];

    const int blk  = blockIdx.x;
    const int g    = blk >> 5;          // group 0..7
    const int rb   = blk & 31;          // block in group 0..31
    const int tid  = threadIdx.x;
    const int lane = tid & 63;
    const int wave = tid >> 6;          // 8 waves: wave = K-eighth
    const int l15  = lane & 15;
    const int q    = lane >> 4;

    // ws: flags 8 groups x 64 uints | h ring 1MB (4 slots) | pbuf ring 128 KB
    unsigned int*   flags = (unsigned int*)ws + g * 64;            // 32 used
    unsigned short* hbuf  = (unsigned short*)((char*)ws + 4096);   // [4][G][GRP_SHORTS]
    float*          pbuf  = (float*)((char*)ws + 4096
                             + (size_t)HSLOTS * GRP_STRIDE * 2);   // [4][G][MPG][64]

    // ---- W' hi-bf16 B-fragments in registers: 8 n-tiles x K/8 = 32 frags ----
    bf16x8 w_hi[8][4];
    #pragma unroll
    for (int ntl = 0; ntl < 8; ++ntl) {
        const int gate = ntl >> 1;
        const int row  = gate * H + rb * DPB + (ntl & 1) * 16 + l15;
        const float* wrow  = Whh + (size_t)row * H;
        const float  wih0r = Wih[row * 2];
        #pragma unroll
        for (int kt = 0; kt < 4; ++kt) {
            const int k0 = wave * 128 + kt * 32 + q * 8;
            #pragma unroll
            for (int j = 0; j < 8; ++j) {
                float w = wrow[k0 + j] + wih0r * Wlin[k0 + j];
                w_hi[ntl][kt][j] = (short)bf16_rne(w);
            }
        }
    }

    // ---- pointwise-thread constants (R5 mapping): pm=bq*4+q, pj=nhi*16+l15 ----
    const int bq    = wave >> 1;              // batch quad 0..3
    const int nhi   = wave & 1;               // dim half 0..1
    const int pm    = bq * 4 + q;             // batch in group 0..15
    const int pj    = nhi * 16 + l15;         // dim within block 0..31
    const int bglob = g * MPG + pm;
    const int kdim  = rb * DPB + pj;
    const float bl  = blin[0];
    float bias_p[4], bias0_p[4], wih0_p[4];
    #pragma unroll
    for (int gt = 0; gt < 4; ++gt) {
        int r2 = gt * H + kdim;
        float b0 = bih[r2] + bhh[r2];
        float w0 = Wih[r2 * 2];
        bias0_p[gt] = b0;
        wih0_p[gt]  = w0;
        bias_p[gt]  = b0 + Wih[r2 * 2 + 1] + w0 * bl;   // folded bias (t>=1)
    }
    float cstate = cell0[(size_t)bglob * H + kdim];
    const float wlin_p = Wlin[kdim];

    // h addressing: chunk layout short index within a (slot,group) region
    const size_t hoff = (size_t)rb * 512 + (pj >> 3) * 128 + pm * 8 + (pj & 7);
    unsigned short* hgrp   = hbuf + (size_t)g * GRP_SHORTS;    // slot 0 of my group
    unsigned short* hpairb = hgrp + hoff;                      // my pair addr (even lanes)
    unsigned short* mychk  = hgrp + (size_t)rb * 512;          // my 1KB chunk, slot 0

    const int4v pois = { (int)POISON, (int)POISON, (int)POISON, (int)POISON };

    // ---- preamble: poison own chunk in ALL 4 slots (before any h0 publish) ----
    if (lane < 8) {
        #pragma unroll
        for (int s = 0; s < HSLOTS; ++s)
            store16_wt((char*)(mychk + (size_t)s * GRP_STRIDE) + wave * 128 + lane * 16,
                       pois);
    }

    // ---- s0[m] = Wlin . h0[m]  (t=0 rank-1 correction; old thread mapping) ----
    {
        const int pm_o = tid >> 5, pj_o = tid & 31;
        const float* hp = hidden0 + (size_t)(g * MPG + pm_o) * H + pj_o * 32;
        const float* wp = Wlin + pj_o * 32;
        float s = 0.f;
        #pragma unroll 4
        for (int kk = 0; kk < 32; kk += 4) {
            float4 hv = *(const float4*)(hp + kk);
            float4 wv = *(const float4*)(wp + kk);
            s += hv.x * wv.x + hv.y * wv.y + hv.z * wv.z + hv.w * wv.w;
        }
        s += __shfl_xor(s, 1); s += __shfl_xor(s, 2);
        s += __shfl_xor(s, 4); s += __shfl_xor(s, 8); s += __shfl_xor(s, 16);
        if (pj_o == 0) s0_lds[pm_o] = s;
    }

    // one-time flag round: all poisons committed before ANY h0 store issues
    asm volatile("s_waitcnt vmcnt(0)" ::: "memory");
    __syncthreads();
    if (tid == 0)
        __hip_atomic_store(&flags[rb], 1u, __ATOMIC_RELAXED, __HIP_MEMORY_SCOPE_AGENT);
    if (wave == 0) {
        for (int spin = 0; spin < SPIN_MAX; ++spin) {
            unsigned int v = __hip_atomic_load(&flags[lane & 31], __ATOMIC_RELAXED,
                                               __HIP_MEMORY_SCOPE_AGENT);
            if (__all((int)(v >= 1u))) break;
        }
    }
    __syncthreads();

    // ---- h0 publish into slot 0: paired-dword, fire-and-forget ----
    {
        float v0 = hidden0[(size_t)bglob * H + kdim];
        unsigned int hs = bf16_rne(v0);
        unsigned int pw = (unsigned int)__shfl_xor((int)hs, 1);
        if (!(lane & 1))
            storeu4_wt(hpairb, (hs & 0xFFFFu) | (pw << 16));
    }

    float pv = 0.f;   // pre-issued pbuf partial (wave1), drained by poll fence

    for (int t = 0; t < T; ++t) {
        // ---- phase A: DATA-POLL this wave's 4 chunks of slot t&3 ----
        const char* hsrc = (const char*)(hgrp + (size_t)(t & 3) * GRP_STRIDE)
                         + wave * 4096 + lane * 16;
        int4v a0, a1, a2, a3;
        for (int spin = 0; spin < SPIN_MAX; ++spin) {
            a0 = load16_nc(hsrc);
            a1 = load16_nc(hsrc + 1024);
            a2 = load16_nc(hsrc + 2048);
            a3 = load16_nc(hsrc + 3072);
            // drain point: commits all of MY prior stores (poison/h/pbuf) and
            // completes these loads + the pre-issued pv load
            asm volatile("s_waitcnt vmcnt(0)"
                         : "+v"(a0), "+v"(a1), "+v"(a2), "+v"(a3), "+v"(pv));
            if (__all(clean4(a0) & clean4(a1) & clean4(a2) & clean4(a3))) break;
        }
        if (wave == 1 && rb < MPG && t >= 3) {
            // batch m = rb: step t-3's 64 partials (pre-issued last phase C)
            float v = pv;
            v += __shfl_xor(v, 1); v += __shfl_xor(v, 2); v += __shfl_xor(v, 4);
            v += __shfl_xor(v, 8); v += __shfl_xor(v, 16); v += __shfl_xor(v, 32);
            if (lane == 0) out[(size_t)(g * MPG + rb) * T + (t - 3)] = v + bl;
        }

        // ---- phase B: MFMA. wave w: 8 n-tiles x 16 batches x K/8 ----
        bf16x8 a[4];
        a[0] = __builtin_bit_cast(bf16x8, a0);
        a[1] = __builtin_bit_cast(bf16x8, a1);
        a[2] = __builtin_bit_cast(bf16x8, a2);
        a[3] = __builtin_bit_cast(bf16x8, a3);
        floatx4 acc[8];
        #pragma unroll
        for (int ntl = 0; ntl < 8; ++ntl) acc[ntl] = (floatx4){0.f, 0.f, 0.f, 0.f};
        #pragma unroll
        for (int kt = 0; kt < 4; ++kt) {
            #pragma unroll
            for (int ntl = 0; ntl < 8; ++ntl)
                acc[ntl] = __builtin_amdgcn_mfma_f32_16x16x32_bf16(a[kt], w_hi[ntl][kt], acc[ntl], 0, 0, 0);
        }
        #pragma unroll
        for (int ntl = 0; ntl < 8; ++ntl)
            *(floatx4*)&Dlds[wave][ntl][l15][q * 4] = acc[ntl];
        __syncthreads();   // post-B: Dlds complete (implicit vmcnt ~free here:
                           // phase-A already drained; lgkmcnt covers ds_writes)

        // ---- phase C (R11 order: poison first, compute, publish, pbuf) ----
        // re-arm: poison my chunk of slot (t+3)&3 == (t-1)&3 (peers' reads of
        // it are certified complete by the merged post-B observations of h_t);
        // issued early so its queue slot drains under the gate compute
        if (lane < 8)
            store16_wt((char*)(mychk + (size_t)((t + 3) & 3) * GRP_STRIDE)
                       + wave * 128 + lane * 16, pois);
        {
            // b128 kk-sum: gate q's chain for dims pj, batches bq*4..+3
            const float* rbase = &Dlds[0][q * 2 + nhi][l15][bq * 4];
            floatx4 S = *(const floatx4*)rbase;
            #pragma unroll
            for (int kk = 1; kk < 8; ++kk)
                S = S + *(const floatx4*)(rbase + kk * 2560);   // kk stride 8*16*20

            // 4x4 transpose across lane quads: gg[i] = gate i, batch bq*4+q
            float a4[4] = {S[0], S[1], S[2], S[3]};
            float cc[4], gg[4];
            #pragma unroll
            for (int j = 0; j < 4; ++j) {
                float tv = __shfl_xor(a4[j ^ 1], 16);
                cc[j] = ((j ^ q) & 1) ? tv : a4[j];
            }
            #pragma unroll
            for (int j = 0; j < 4; ++j) {
                float tv = __shfl_xor(cc[j ^ 2], 32);
                gg[j] = ((j ^ q) & 2) ? tv : cc[j];
            }

            float gv[4];
            if (t == 0) {
                float s0 = s0_lds[pm];
                #pragma unroll
                for (int gt = 0; gt < 4; ++gt) gv[gt] = gg[gt] + bias0_p[gt] - wih0_p[gt] * s0;
            } else {
                #pragma unroll
                for (int gt = 0; gt < 4; ++gt) gv[gt] = gg[gt] + bias_p[gt];
            }
            float ig  = sigmoidf_(gv[0]);
            float fg  = sigmoidf_(gv[1]);
            float gt_ = tanhf_fast(gv[2]);
            float og  = sigmoidf_(gv[3]);
            cstate = fg * cstate + ig * gt_;
            float hnew = og * tanhf_fast(cstate);

            // h publish into slot (t+1)&3: paired-dword (atomic, never torn),
            // fire-and-forget — consumers' data-polls detect arrival directly
            unsigned int hs = bf16_rne(hnew);
            unsigned int pw = (unsigned int)__shfl_xor((int)hs, 1);
            if (!(lane & 1))
                storeu4_wt(hpairb + (size_t)((t + 1) & 3) * GRP_STRIDE,
                           (hs & 0xFFFFu) | (pw << 16));

            // po partial per (batch, dim-half): reduce over 16 dim lanes
            float po = wlin_p * hnew;
            po += __shfl_xor(po, 1); po += __shfl_xor(po, 2);
            po += __shfl_xor(po, 4); po += __shfl_xor(po, 8);
            if (l15 == 0)
                store4_wt(pbuf + (size_t)(((t & 3) * GROUPS + g) * MPG + pm) * 64
                          + nhi * 32 + rb, po);
        }

        // ---- pre-issue step t+1's pbuf read (wave1; slot (t-2)&3, certified
        //      committed by this step's post-B all-32 merge) — R9-proven ----
        if (wave == 1 && rb < MPG && t >= 2 && t < T - 1) {
            const float* pr = pbuf + (size_t)((((t - 2) & 3) * GROUPS + g) * MPG + rb) * 64;
            pv = load4_nc(pr + lane);
        }

        // ---- post-C sync: RAW barrier — LDS ordering + poll-window bounding
        //      (R12 proved this rendezvous is load-bearing for performance).
        //      WT stores stay in flight; they ack during the next poll RTT. ----
        asm volatile("s_waitcnt lgkmcnt(0)" ::: "memory");
        __builtin_amdgcn_s_barrier();
        __builtin_amdgcn_sched_barrier(0);
    }

    // ---- epilogue: one flag round orders final pbuf commits, then T-3..T-1 ----
    asm volatile("s_waitcnt vmcnt(0)" ::: "memory");
    __syncthreads();
    if (tid == 0)
        __hip_atomic_store(&flags[rb], 2u, __ATOMIC_RELAXED, __HIP_MEMORY_SCOPE_AGENT);
    if (wave == 1 && rb < MPG) {
        for (int spin = 0; spin < SPIN_MAX; ++spin) {
            unsigned int v = __hip_atomic_load(&flags[lane & 31], __ATOMIC_RELAXED,
                                               __HIP_MEMORY_SCOPE_AGENT);
            if (__all((int)(v >= 2u))) break;
        }
        for (int tt = T - 3; tt < T; ++tt) {
            const float* pr = pbuf + (size_t)(((tt & 3) * GROUPS + g) * MPG + rb) * 64;
            float v = load4_ncw(pr + lane);
            v += __shfl_xor(v, 1); v += __shfl_xor(v, 2); v += __shfl_xor(v, 4);
            v += __shfl_xor(v, 8); v += __shfl_xor(v, 16); v += __shfl_xor(v, 32);
            if (lane == 0) out[(size_t)(g * MPG + rb) * T + tt] = v + bl;
        }
    }
}

extern "C" void kernel_launch(void* const* d_in, const int* in_sizes, int n_in,
                              void* d_out, int out_size, void* d_ws, size_t ws_size,
                              hipStream_t stream) {
    const float* hidden0 = (const float*)d_in[0];
    const float* cell0   = (const float*)d_in[1];
    const float* Wih     = (const float*)d_in[2];
    const float* Whh     = (const float*)d_in[3];
    const float* bih     = (const float*)d_in[4];
    const float* bhh     = (const float*)d_in[5];
    const float* Wlin    = (const float*)d_in[6];
    const float* blin    = (const float*)d_in[7];
    float* out = (float*)d_out;
    float* ws  = (float*)d_ws;

    // zero the preamble/epilogue flags
    hipMemsetAsync(d_ws, 0, 4096, stream);

    void* args[] = { &hidden0, &cell0, &Wih, &Whh, &bih, &bhh, &Wlin, &blin,
                     &out, &ws };
    hipLaunchCooperativeKernel((const void*)decoder_kernel,
                               dim3(GROUPS * BPG), dim3(NTHR), args, 0, stream);
}